// Round 2
// baseline (5547.837 us; speedup 1.0000x reference)
//
#include <hip/hip_runtime.h>

// LocalAttention P=7 window attention, bf16-MFMA rewrite.
// x:[32,192,56,56] f32 -> out:[32,192,56,56] f32 ++ attn:[2048,8,49,49] f32

#define NT 49
#define NWIN 2048
#define OUT0 19267584L

typedef __attribute__((ext_vector_type(8))) short bf16x8;
typedef __attribute__((ext_vector_type(4))) float f32x4;

#define MFMA(a, b, c) __builtin_amdgcn_mfma_f32_16x16x32_bf16(a, b, c, 0, 0, 0)

__device__ __forceinline__ unsigned short f2b(float f) {
  unsigned u = __builtin_bit_cast(unsigned, f);
  return (unsigned short)((u + 0x7FFFu + ((u >> 16) & 1u)) >> 16);
}
__device__ __forceinline__ unsigned pk2(float a, float b) {
  return (unsigned)f2b(a) | ((unsigned)f2b(b) << 16);
}
__device__ __forceinline__ float b2f(unsigned short h) {
  unsigned u = ((unsigned)h) << 16;
  return __builtin_bit_cast(float, u);
}

// ---- workspace layout (bytes) ----
#define XT_BYTES (2048L * 64 * 192 * 2)   // 50,331,648  xt[win][t(64)][c(192)] bf16
#define WQKV_OFF XT_BYTES
#define WO_OFF   (WQKV_OFF + 768L * 192 * 2)
#define BIAS_OFF (WO_OFF + 192L * 256 * 2)

// ---------------- prep: weights->bf16, bias table ----------------
__global__ __launch_bounds__(256) void prep_kernel(
    const float* __restrict__ mask, const float* __restrict__ Wq,
    const float* __restrict__ Wkv, const float* __restrict__ Wo,
    const float* __restrict__ pos,
    unsigned short* __restrict__ wqkv, unsigned short* __restrict__ wo,
    float* __restrict__ bias)
{
  int stride = gridDim.x * blockDim.x;
  int t0 = blockIdx.x * blockDim.x + threadIdx.x;
  for (int i = t0; i < 768 * 192; i += stride)
    wqkv[i] = f2b(i < 256 * 192 ? Wq[i] : Wkv[i - 256 * 192]);
  for (int i = t0; i < 192 * 256; i += stride)
    wo[i] = f2b(Wo[i]);
  for (int i = t0; i < 49 * 49; i += stride) {
    int tq = i / 49, tk = i - tq * 49;
    int r0 = tk / 7 - tq / 7 + 6, r1 = tk % 7 - tq % 7 + 6;
    bias[i] = mask[i] + pos[r0 * 13 + r1];
  }
}

// ---------------- xt: window-partition + transpose + bf16 ----------------
__global__ __launch_bounds__(256) void xt_kernel(const float* __restrict__ x,
                                                 unsigned short* __restrict__ xt)
{
  __shared__ float sXw[192][53];  // pad 53: stride 21 mod 32, conflict-free
  const int tid = threadIdx.x;
  const int widx = blockIdx.x;
  const int bi = widx >> 6, w1 = (widx >> 3) & 7, w2 = widx & 7;
  const long xbase = (long)bi * 192 * 3136 + (w1 * 7) * 56 + w2 * 7;

  for (int idx = tid; idx < 192 * 49; idx += 256) {
    int c = idx / 49, t = idx - c * 49;
    sXw[c][t] = x[xbase + c * 3136 + (t / 7) * 56 + (t % 7)];
  }
  __syncthreads();
  unsigned short* xw = xt + (long)widx * 64 * 192;
  for (int idx = tid; idx < 64 * 192; idx += 256) {
    int t = idx / 192, c = idx - t * 192;
    xw[idx] = (t < 49) ? f2b(sXw[c][t]) : (unsigned short)0;  // zero pad rows
  }
}

// ---------------- main fused kernel: 1 block = 1 window, 8 waves ----------------
// LDS regions (byte offsets):
//   Q  [64t][256e] bf16 swz : 0      .. 32768   (row 512B)
//   K  [64t][256e] bf16 swz : 32768  .. 65536
//   Vt [256e][64t] bf16 swz : 65536  .. 98304   (row 128B)
//   P  8 x [52tq][64tk] swz : 98304  .. 151552  (row 128B, 6656B/wave)
//   O aliases Q (after B2); outbuf[49][196] f32 aliases K..P (after B3)
#define QOFF  0
#define KOFF  32768
#define VOFF  65536
#define POFF  98304
#define OBOFF 32768
#define LDS_TOTAL 151552

__global__ __launch_bounds__(512, 1) void la_main(
    const unsigned short* __restrict__ xt, const unsigned short* __restrict__ wqkv,
    const unsigned short* __restrict__ wo, const float* __restrict__ bias,
    const float* __restrict__ bo, float* __restrict__ attn_out,
    float* __restrict__ out)
{
  __shared__ __align__(16) char lds[LDS_TOTAL];

  const int tid = threadIdx.x;
  const int w = tid >> 6;           // wave 0..7
  const int lane = tid & 63;
  const int l15 = lane & 15;
  const int lg = lane >> 4;         // 0..3
  const int widx = blockIdx.x;
  const int bi = widx >> 6, w1 = (widx >> 3) & 7, w2 = widx & 7;
  const unsigned short* xw = xt + (long)widx * 64 * 192;
  const f32x4 zero = {0.f, 0.f, 0.f, 0.f};

  // ================= P1: QKV projection =================
  // QK: D[e][t] = W[e][c] x xt[t][c]^T ; wave w owns Wqkv rows w*64..w*64+63
  // V : D[t][e] = xt[t][c] x Wv[e][c]^T; wave w owns v-rows w*32..w*32+31
  f32x4 acc[4][4];   // [mi: e-sub 16][ni: t-tile 16]
  f32x4 accv[4][2];  // [mi: t-tile][nj: e-sub]
  #pragma unroll
  for (int i = 0; i < 4; ++i)
    #pragma unroll
    for (int j = 0; j < 4; ++j) acc[i][j] = zero;
  #pragma unroll
  for (int i = 0; i < 4; ++i)
    #pragma unroll
    for (int j = 0; j < 2; ++j) accv[i][j] = zero;

  #pragma unroll
  for (int ks = 0; ks < 6; ++ks) {
    const int kc = ks * 32 + lg * 8;
    bf16x8 a[4], b[4], bv[2];
    #pragma unroll
    for (int mi = 0; mi < 4; ++mi)
      a[mi] = *(const bf16x8*)(wqkv + (w * 64 + mi * 16 + l15) * 192 + kc);
    #pragma unroll
    for (int ni = 0; ni < 4; ++ni)
      b[ni] = *(const bf16x8*)(xw + (ni * 16 + l15) * 192 + kc);
    #pragma unroll
    for (int nj = 0; nj < 2; ++nj)
      bv[nj] = *(const bf16x8*)(wqkv + (512 + w * 32 + nj * 16 + l15) * 192 + kc);
    #pragma unroll
    for (int mi = 0; mi < 4; ++mi)
      #pragma unroll
      for (int ni = 0; ni < 4; ++ni)
        acc[mi][ni] = MFMA(a[mi], b[ni], acc[mi][ni]);
    #pragma unroll
    for (int mi = 0; mi < 4; ++mi)   // V: A-operand = xt frags (same layout as b)
      #pragma unroll
      for (int nj = 0; nj < 2; ++nj)
        accv[mi][nj] = MFMA(b[mi], bv[nj], accv[mi][nj]);
  }
  // write QK: row t, 4 consecutive e -> packed b64, swizzled
  {
    char* qk = lds + (w < 4 ? QOFF : KOFF);
    const int ebase = (w & 3) * 64;
    #pragma unroll
    for (int mi = 0; mi < 4; ++mi)
      #pragma unroll
      for (int ni = 0; ni < 4; ++ni) {
        int t = ni * 16 + l15;
        int e0 = ebase + mi * 16 + lg * 4;
        uint2 v = {pk2(acc[mi][ni][0], acc[mi][ni][1]),
                   pk2(acc[mi][ni][2], acc[mi][ni][3])};
        *(uint2*)(qk + t * 512 + ((e0 * 2) ^ ((t & 7) << 4))) = v;
      }
    #pragma unroll
    for (int mi = 0; mi < 4; ++mi)
      #pragma unroll
      for (int nj = 0; nj < 2; ++nj) {
        int e = w * 32 + nj * 16 + l15;
        int t0 = mi * 16 + lg * 4;
        uint2 v = {pk2(accv[mi][nj][0], accv[mi][nj][1]),
                   pk2(accv[mi][nj][2], accv[mi][nj][3])};
        *(uint2*)(lds + VOFF + e * 128 + ((t0 * 2) ^ ((e & 7) << 4))) = v;
      }
  }
  __syncthreads();  // B1

  // ================= P2: S = K.Q^T (per wave = head w), softmax, P =================
  f32x4 s[4][4];  // [mi: tk-tile][ni: tq-tile]
  {
    const int dc = (w * 32 + lg * 8) * 2;  // byte col of d-chunk
    bf16x8 ak[4], bq[4];
    #pragma unroll
    for (int mi = 0; mi < 4; ++mi) {
      int tk = mi * 16 + l15;
      ak[mi] = *(const bf16x8*)(lds + KOFF + tk * 512 + (dc ^ ((tk & 7) << 4)));
    }
    #pragma unroll
    for (int ni = 0; ni < 4; ++ni) {
      int tq = ni * 16 + l15;
      bq[ni] = *(const bf16x8*)(lds + QOFF + tq * 512 + (dc ^ ((tq & 7) << 4)));
    }
    #pragma unroll
    for (int mi = 0; mi < 4; ++mi)
      #pragma unroll
      for (int ni = 0; ni < 4; ++ni)
        s[mi][ni] = MFMA(ak[mi], bq[ni], zero);
  }
  const float scale = 0.17677669529663687f;
  #pragma unroll
  for (int ni = 0; ni < 4; ++ni) {
    int tq = ni * 16 + l15;
    int tqc = tq < 49 ? tq : 48;
    #pragma unroll
    for (int mi = 0; mi < 4; ++mi)
      #pragma unroll
      for (int r = 0; r < 4; ++r) {
        int tk = mi * 16 + lg * 4 + r;
        float v = s[mi][ni][r];
        s[mi][ni][r] = (tk < 49) ? (v * scale + bias[tqc * 49 + tk]) : -1e30f;
      }
    float m = -1e30f;
    #pragma unroll
    for (int mi = 0; mi < 4; ++mi)
      #pragma unroll
      for (int r = 0; r < 4; ++r) m = fmaxf(m, s[mi][ni][r]);
    m = fmaxf(m, __shfl_xor(m, 16));
    m = fmaxf(m, __shfl_xor(m, 32));
    float sum = 0.f;
    #pragma unroll
    for (int mi = 0; mi < 4; ++mi)
      #pragma unroll
      for (int r = 0; r < 4; ++r) {
        float e = __expf(s[mi][ni][r] - m);
        s[mi][ni][r] = e;
        sum += e;
      }
    sum += __shfl_xor(sum, 16);
    sum += __shfl_xor(sum, 32);
    float inv = 1.0f / sum;
    #pragma unroll
    for (int mi = 0; mi < 4; ++mi)
      #pragma unroll
      for (int r = 0; r < 4; ++r) s[mi][ni][r] *= inv;
  }
  // write P (bf16, per-wave region, 52 rows)
  {
    char* pw = lds + POFF + w * 6656;
    #pragma unroll
    for (int ni = 0; ni < 4; ++ni) {
      int tq = ni * 16 + l15;
      if (tq < 52) {
        #pragma unroll
        for (int mi = 0; mi < 4; ++mi) {
          int tk0 = mi * 16 + lg * 4;
          uint2 v = {pk2(s[mi][ni][0], s[mi][ni][1]),
                     pk2(s[mi][ni][2], s[mi][ni][3])};
          *(uint2*)(pw + tq * 128 + ((tk0 * 2) ^ ((tq & 7) << 4))) = v;
        }
      }
    }
  }
  __syncthreads();  // B2 (orders P for all waves; Q now dead -> O aliases Q)

  // ================= P3: O = V.P^T (per wave = head w) + attn write =================
  {
    f32x4 o[2][4];
    #pragma unroll
    for (int i = 0; i < 2; ++i)
      #pragma unroll
      for (int j = 0; j < 4; ++j) o[i][j] = zero;
    #pragma unroll
    for (int ks = 0; ks < 2; ++ks) {
      const int tkc = (ks * 32 + lg * 8) * 2;
      bf16x8 av[2], bp[4];
      #pragma unroll
      for (int mi = 0; mi < 2; ++mi) {
        int d = w * 32 + mi * 16 + l15;  // Vt row (e-global)
        av[mi] = *(const bf16x8*)(lds + VOFF + d * 128 + (tkc ^ ((d & 7) << 4)));
      }
      #pragma unroll
      for (int ni = 0; ni < 4; ++ni) {
        int tq = ni * 16 + l15;
        if (tq > 48) tq = 48;  // clamp into 52-row P buffer (garbage cols)
        bp[ni] = *(const bf16x8*)(lds + POFF + w * 6656 + tq * 128 + (tkc ^ ((tq & 7) << 4)));
      }
      #pragma unroll
      for (int mi = 0; mi < 2; ++mi)
        #pragma unroll
        for (int ni = 0; ni < 4; ++ni)
          o[mi][ni] = MFMA(av[mi], bp[ni], o[mi][ni]);
    }
    // write O[tq][e] (aliases Q): row tq, 4 consecutive e
    #pragma unroll
    for (int mi = 0; mi < 2; ++mi)
      #pragma unroll
      for (int ni = 0; ni < 4; ++ni) {
        int tq = ni * 16 + l15;
        int e0 = w * 32 + mi * 16 + lg * 4;
        uint2 v = {pk2(o[mi][ni][0], o[mi][ni][1]),
                   pk2(o[mi][ni][2], o[mi][ni][3])};
        *(uint2*)(lds + QOFF + tq * 512 + ((e0 * 2) ^ ((tq & 7) << 4))) = v;
      }
  }
  // attn output, coalesced from P_lds
  {
    float* abase = attn_out + (long)widx * (8 * 49 * 49);
    for (int idx = tid; idx < 8 * 49 * 49; idx += 512) {
      int h = idx / 2401;
      int r = idx - h * 2401;
      int tq = r / 49, tk = r - tq * 49;
      unsigned short pv =
          *(const unsigned short*)(lds + POFF + h * 6656 + tq * 128 + ((tk * 2) ^ ((tq & 7) << 4)));
      abase[idx] = b2f(pv);
    }
  }
  __syncthreads();  // B3 (O complete; P/K dead -> outbuf aliases)

  // ================= P4: out-proj D[oc][t] = Wo[oc][e] x O[t][e]^T =================
  {
    f32x4 po[6];
    #pragma unroll
    for (int q = 0; q < 6; ++q) po[q] = zero;
    const int id0 = w * 6;
    const int oct0 = id0 >> 2;
    #pragma unroll
    for (int ks = 0; ks < 8; ++ks) {
      const int ec = ks * 32 + lg * 8;
      bf16x8 a2[2], bO[4];
      #pragma unroll
      for (int i = 0; i < 2; ++i)
        a2[i] = *(const bf16x8*)(wo + ((oct0 + i) * 16 + l15) * 256 + ec);
      #pragma unroll
      for (int tt = 0; tt < 4; ++tt) {
        int t = tt * 16 + l15;
        bO[tt] = *(const bf16x8*)(lds + QOFF + t * 512 + ((ec * 2) ^ ((t & 7) << 4)));
      }
      #pragma unroll
      for (int q = 0; q < 6; ++q) {
        int id = id0 + q;
        po[q] = MFMA(a2[(id >> 2) - oct0], bO[id & 3], po[q]);
      }
    }
    // outbuf[t][196 oc] f32 (aliases K..P region)
    #pragma unroll
    for (int q = 0; q < 6; ++q) {
      int id = id0 + q;
      int oc0 = (id >> 2) * 16 + lg * 4;
      int t = (id & 3) * 16 + l15;
      if (t < 49)
        *(f32x4*)(lds + OBOFF + (t * 196 + oc0) * 4) = po[q];
    }
  }
  __syncthreads();  // B4

  // final coalesced-ish global write (+bo)
  {
    const long obase = (long)bi * 602112 + (w1 * 7) * 56 + w2 * 7;
    for (int idx = tid; idx < 192 * 49; idx += 512) {
      int oc = idx / 49, t = idx - oc * 49;
      float v = *(const float*)(lds + OBOFF + (t * 196 + oc) * 4) + bo[oc];
      out[obase + oc * 3136 + (t / 7) * 56 + (t % 7)] = v;
    }
  }
}

extern "C" void kernel_launch(void* const* d_in, const int* in_sizes, int n_in,
                              void* d_out, int out_size, void* d_ws, size_t ws_size,
                              hipStream_t stream)
{
  const float* x    = (const float*)d_in[0];
  const float* mask = (const float*)d_in[1];
  const float* Wq   = (const float*)d_in[2];
  const float* Wkv  = (const float*)d_in[3];
  const float* Wo   = (const float*)d_in[4];
  const float* bo   = (const float*)d_in[5];
  const float* pos  = (const float*)d_in[6];

  float* out  = (float*)d_out;
  float* attn = out + OUT0;

  char* ws = (char*)d_ws;
  unsigned short* xt   = (unsigned short*)(ws);
  unsigned short* wqkv = (unsigned short*)(ws + WQKV_OFF);
  unsigned short* wo   = (unsigned short*)(ws + WO_OFF);
  float*          bias = (float*)(ws + BIAS_OFF);

  prep_kernel<<<256, 256, 0, stream>>>(mask, Wq, Wkv, Wo, pos, wqkv, wo, bias);
  xt_kernel<<<NWIN, 256, 0, stream>>>(x, xt);
  la_main<<<NWIN, 512, 0, stream>>>(xt, wqkv, wo, bias, bo, attn, out);
}